// Round 9
// baseline (321.624 us; speedup 1.0000x reference)
//
#include <hip/hip_runtime.h>
#include <math.h>

// (B, CK, CV, T, H, W) = (2, 64, 256, 8, 48, 48)
#define NB 2
#define CVD 256
#define TD 8
#define HWD 2304
#define THWD 18432
#define QB 64
#define NQB 36            // HWD/QB

typedef __bf16 bf16_t;
typedef __bf16 bf16x8 __attribute__((ext_vector_type(8)));
typedef float f32x4 __attribute__((ext_vector_type(4)));
typedef float f32x16 __attribute__((ext_vector_type(16)));
typedef unsigned u32;

__device__ __forceinline__ void gload16(const void* g, void* l) {
    __builtin_amdgcn_global_load_lds((const __attribute__((address_space(1))) u32*)g,
                                     (__attribute__((address_space(3))) u32*)l, 16, 0, 0);
}
__device__ __forceinline__ u32 cvtpk(float lo, float hi) {
    u32 r;
    asm("v_cvt_pk_bf16_f32 %0, %1, %2" : "=v"(r) : "v"(lo), "v"(hi));
    return r;
}
union U8 { u32 u[4]; bf16x8 v; };

// ---------------------------------------------------------------------------
// prep_kf: KFG[b][kv][slot 16]x16B, slot = cg ^ (kv&15) (inverse of the fused
// read swizzle: linear global_load_lds dest + pre-swizzled source).
// content ch = cg*8+e: mk (ch<64) | mk^2 (ch>=64), bf16.
// ---------------------------------------------------------------------------
__global__ void prep_kf(const float* __restrict__ mk, char* __restrict__ KFG) {
    __shared__ float tile[64][65];
    const int b = blockIdx.y;
    const int kv0 = blockIdx.x * 64;
    const int tid = threadIdx.x;
    {
        const int ci = tid >> 2, seg = tid & 3;
        const float* src = mk + ((size_t)b * 64 + ci) * THWD + kv0;
#pragma unroll
        for (int j = 0; j < 4; ++j) {
            int chk = seg + j * 4;
            f32x4 v = *(const f32x4*)(src + chk * 4);
#pragma unroll
            for (int x = 0; x < 4; ++x) tile[ci][chk * 4 + x] = v[x];
        }
    }
    __syncthreads();
#pragma unroll
    for (int k = 0; k < 4; ++k) {
        int gid = k * 256 + tid;          // 1024 granules: 64 kv x 16 cg
        int kvl = gid >> 4, cg = gid & 15;
        bf16x8 o;
#pragma unroll
        for (int e = 0; e < 8; ++e) {
            int ch = cg * 8 + e;
            float v;
            if (ch < 64) v = tile[ch][kvl];
            else { float m = tile[ch - 64][kvl]; v = m * m; }
            o[e] = (bf16_t)v;
        }
        int slot = cg ^ (kvl & 15);
        size_t byte = ((size_t)b * THWD + kv0 + kvl) * 256 + slot * 16;
        *(bf16x8*)(KFG + byte) = o;
    }
}

// ---------------------------------------------------------------------------
// prep_qf: QFG[b][qb32][ks 8][q32][hi 2]x16B (direct 32x32x16 B-frag order),
// content ch = ks*16+hi*8+e: 2*qk*qe (ch<64) | -qe. bsq[b][q] fp32.
// ---------------------------------------------------------------------------
__global__ void prep_qf(const float* __restrict__ qk, const float* __restrict__ qe,
                        char* __restrict__ QFG, float* __restrict__ bsq) {
    __shared__ float tk[64][65];
    __shared__ float te[64][65];
    __shared__ float bs[4][64];
    const int b = blockIdx.y;
    const int q0 = blockIdx.x * 64;
    const int tid = threadIdx.x;
    {
        const int ci = tid >> 2, seg = tid & 3;
        const float* s1 = qk + ((size_t)b * 64 + ci) * HWD + q0;
        const float* s2 = qe + ((size_t)b * 64 + ci) * HWD + q0;
#pragma unroll
        for (int j = 0; j < 4; ++j) {
            int chk = seg + j * 4;
            f32x4 v1 = *(const f32x4*)(s1 + chk * 4);
            f32x4 v2 = *(const f32x4*)(s2 + chk * 4);
#pragma unroll
            for (int x = 0; x < 4; ++x) { tk[ci][chk * 4 + x] = v1[x]; te[ci][chk * 4 + x] = v2[x]; }
        }
    }
    __syncthreads();
    {
        int qls = tid & 63, cp = tid >> 6;
        float s = 0.f;
#pragma unroll
        for (int cc = 0; cc < 16; ++cc) {
            int ch = cp * 16 + cc;
            float kk = tk[ch][qls];
            s = fmaf(te[ch][qls] * kk, kk, s);
        }
        bs[cp][qls] = s;
    }
#pragma unroll
    for (int k = 0; k < 4; ++k) {
        int gid = k * 256 + tid;
        int qll = gid >> 4, G = gid & 15;
        int ks = G >> 1, h2 = G & 1;
        bf16x8 o;
#pragma unroll
        for (int e = 0; e < 8; ++e) {
            int ch = ks * 16 + h2 * 8 + e;
            float v;
            if (ch < 64) v = 2.f * tk[ch][qll] * te[ch][qll];
            else v = -te[ch - 64][qll];
            o[e] = (bf16_t)v;
        }
        size_t byte = ((size_t)b * 72 + (q0 >> 5) + (qll >> 5)) * 8192 +
                      (size_t)(((ks * 32 + (qll & 31)) * 2 + h2) * 16);
        *(bf16x8*)(QFG + byte) = o;
    }
    __syncthreads();
    if (tid < 64) bsq[b * HWD + q0 + tid] = bs[0][tid] + bs[1][tid] + bs[2][tid] + bs[3][tid];
}

// ---------------------------------------------------------------------------
// mv_t: MVT[b][t16][cv 256][hi 2]x16B (direct 32x32x16 A-frag order),
// content mv[cv][t16*16+hi*8+e] bf16.  Also msf = ms * 0.125 (fp32).
// ---------------------------------------------------------------------------
__global__ void mv_t(const float* __restrict__ mv, const float* __restrict__ ms,
                     char* __restrict__ MVT, float* __restrict__ msf) {
    __shared__ float tile[64][65];
    const int b = blockIdx.z;
    const int cv0 = blockIdx.y * 64;
    const int kv0 = blockIdx.x * 64;
    const int tid = threadIdx.x;
    {
        const int cvl = tid >> 2, seg = tid & 3;
        const float* src = mv + ((size_t)b * CVD + cv0 + cvl) * THWD + kv0;
#pragma unroll
        for (int j = 0; j < 4; ++j) {
            int chk = seg + j * 4;
            f32x4 v = *(const f32x4*)(src + chk * 4);
#pragma unroll
            for (int x = 0; x < 4; ++x) tile[cvl][chk * 4 + x] = v[x];
        }
    }
    if (blockIdx.y == 0 && tid < 64)
        msf[b * THWD + kv0 + tid] = ms[b * THWD + kv0 + tid] * 0.125f;
    __syncthreads();
#pragma unroll
    for (int k = 0; k < 2; ++k) {
        int gid = k * 256 + tid;          // 512 granules: 64 cv x 4 t16 x 2 hi
        int cvl = gid >> 3, gg = gid & 7;
        int t16l = gg >> 1, h2 = gg & 1;
        bf16x8 o;
#pragma unroll
        for (int e = 0; e < 8; ++e) o[e] = (bf16_t)tile[cvl][t16l * 16 + h2 * 8 + e];
        size_t byte = ((size_t)(b * 1152 + (kv0 >> 4) + t16l) * 256 + cv0 + cvl) * 32 +
                      (size_t)(h2 * 16);
        *(bf16x8*)(MVT + byte) = o;
    }
}

// ---------------------------------------------------------------------------
// fused: 256 thr = 4 waves = (ch: cv 128-half) x (qh: q 32-half), 32x32x16.
// Tile = 32 kv. acc = 64 VGPR/wave. QK ch-duplicated, DUAL accumulator chains
// (halves the serial MFMA dependency); softmax + w in-register (cvt_pk +
// permlane32_swap); mv global->reg; kf double-buffered via global_load_lds;
// 1 barrier + vmcnt(0) per tile. Scores <= 0 -> no max bookkeeping;
// split-T partials are plain sums. split*tiles*32 == THWD exactly.
// ---------------------------------------------------------------------------
__global__ __launch_bounds__(256, 3) void fused(
    const char* __restrict__ KFG, const char* __restrict__ QFG,
    const char* __restrict__ MVT, const float* __restrict__ msf,
    const float* __restrict__ bsq, float* __restrict__ accP,
    float* __restrict__ lP, int split, int tiles) {
    __shared__ __align__(16) char kf_s[2][8192];

    const int tid = threadIdx.x;
    const int lane = tid & 63;
    const int wave = tid >> 6;
    const int qh = wave & 1;
    const int ch = wave >> 1;
    const int c = lane & 31;
    const int hi = lane >> 5;
    const int x15 = c & 15;

    // XCD clustering: consecutive ids per XCD share (b,sp) groups
    const int bid = blockIdx.x;
    const int chunk = gridDim.x >> 3;
    const int id = (bid & 7) * chunk + (bid >> 3);
    const int qblk = id % NQB;
    const int rest = id / NQB;
    const int b = rest / split;
    const int sp = rest % split;
    const int t32base = sp * tiles;

    const char* KFb = KFG + (size_t)b * THWD * 256;
    const char* QFb = QFG + (size_t)b * 72 * 8192;
    const char* MVb = MVT + (size_t)b * 1152 * 8192;
    const float* msfb = msf + (size_t)b * THWD;

    // stage: per instruction, LDS dest = wave-uniform base + lane*16 (HW rule)
    auto stage = [&](int buf, int it) {
        const char* g = KFb + (size_t)(t32base + it) * 8192 + wave * 2048 + lane * 16;
        char* l = &kf_s[buf][wave * 2048 + lane * 16];
        gload16(g, l);
        gload16(g + 1024, l + 1024);
    };
    stage(0, 0);

    // resident q fragments ks 0..3 (ks 4..7 re-read per tile, L1-hot) + bsq
    const char* qt = QFb + (size_t)(qblk * 2 + qh) * 8192;
    bf16x8 qfr[4];
#pragma unroll
    for (int ks = 0; ks < 4; ++ks)
        qfr[ks] = *(const bf16x8*)(qt + ((ks * 32 + c) * 2 + hi) * 16);
    const float bsqr = bsq[b * HWD + qblk * 64 + qh * 32 + c];

    f32x16 acc[4];
#pragma unroll
    for (int i = 0; i < 4; ++i)
#pragma unroll
        for (int e = 0; e < 16; ++e) acc[i][e] = 0.f;
    float lacc = 0.f;

#pragma unroll 2
    for (int it = 0; it < tiles; ++it) {
        const int t0 = (t32base + it) * 32;
        const char* kc = kf_s[it & 1];

        // only pending VMEM of consequence is stage(it); drain + barrier
        asm volatile("s_waitcnt vmcnt(0)" ::: "memory");
        __builtin_amdgcn_s_barrier();

        // mv A-frags batch 0 (global, L2-resident; lands during QK)
        const char* mt = MVb + (size_t)(t0 >> 4) * 8192 + ((ch * 128 + c) * 2 + hi) * 16;
        bf16x8 mvf0[4];
#pragma unroll
        for (int cvb = 0; cvb < 4; ++cvb) mvf0[cvb] = *(const bf16x8*)(mt + cvb * 1024);

        if (it + 1 < tiles) stage((it + 1) & 1, it + 1);

        // QK, dual independent accumulator chains (shorter critical path)
        f32x16 Sa, Sb;
#pragma unroll
        for (int e = 0; e < 16; ++e) { Sa[e] = 0.f; Sb[e] = 0.f; }
#pragma unroll
        for (int ks = 0; ks < 4; ++ks) {
            bf16x8 kfa = *(const bf16x8*)(kc + c * 256 + ((((ks << 1) | hi) ^ x15) << 4));
            Sa = __builtin_amdgcn_mfma_f32_32x32x16_bf16(kfa, qfr[ks], Sa, 0, 0, 0);
        }
#pragma unroll
        for (int ks = 4; ks < 8; ++ks) {
            bf16x8 kfb = *(const bf16x8*)(kc + c * 256 + ((((ks << 1) | hi) ^ x15) << 4));
            bf16x8 qv = *(const bf16x8*)(qt + ((ks * 32 + c) * 2 + hi) * 16);
            Sb = __builtin_amdgcn_mfma_f32_32x32x16_bf16(kfb, qv, Sb, 0, 0, 0);
        }

        // mv batch 1 (lands during exp+pack+PV0)
        bf16x8 mvf1[4];
#pragma unroll
        for (int cvb = 0; cvb < 4; ++cvb)
            mvf1[cvb] = *(const bf16x8*)(mt + 8192 + cvb * 1024);

        // w = exp((S - bsq) * ms/8); scores <= 0 so no max bookkeeping
        f32x16 S;
#pragma unroll
        for (int rq = 0; rq < 4; ++rq) {
            f32x4 m4 = *(const f32x4*)(msfb + t0 + rq * 8 + hi * 4);
#pragma unroll
            for (int j = 0; j < 4; ++j) {
                int e = rq * 4 + j;
                S[e] = __expf(((Sa[e] + Sb[e]) - bsqr) * m4[j]);
            }
        }
        if (ch == 0) {
#pragma unroll
            for (int e = 0; e < 16; ++e) lacc += S[e];
        }

        // pack to bf16 + permlane32_swap -> PV B-frags in-register
        u32 p[8];
#pragma unroll
        for (int j = 0; j < 8; ++j) p[j] = cvtpk(S[2 * j], S[2 * j + 1]);
        asm("v_permlane32_swap_b32 %0, %1" : "+v"(p[0]), "+v"(p[2]));
        asm("v_permlane32_swap_b32 %0, %1" : "+v"(p[1]), "+v"(p[3]));
        asm("v_permlane32_swap_b32 %0, %1" : "+v"(p[4]), "+v"(p[6]));
        asm("v_permlane32_swap_b32 %0, %1" : "+v"(p[5]), "+v"(p[7]));
        U8 wf0, wf1;
        wf0.u[0] = p[0]; wf0.u[1] = p[1]; wf0.u[2] = p[2]; wf0.u[3] = p[3];
        wf1.u[0] = p[4]; wf1.u[1] = p[5]; wf1.u[2] = p[6]; wf1.u[3] = p[7];

        // PV: acc[cv][q] += mv[cv][kv] * w[kv][q], K=32 as 2x K16
#pragma unroll
        for (int cvb = 0; cvb < 4; ++cvb)
            acc[cvb] = __builtin_amdgcn_mfma_f32_32x32x16_bf16(mvf0[cvb], wf0.v, acc[cvb], 0, 0, 0);
#pragma unroll
        for (int cvb = 0; cvb < 4; ++cvb)
            acc[cvb] = __builtin_amdgcn_mfma_f32_32x32x16_bf16(mvf1[cvb], wf1.v, acc[cvb], 0, 0, 0);
    }

    // epilogue: direct fp32 partial stores (each output element written once)
    const size_t pb = (size_t)(b * NQB + qblk) * split + sp;
    float* accB = accP + pb * (CVD * QB);
#pragma unroll
    for (int cvb = 0; cvb < 4; ++cvb)
#pragma unroll
        for (int rq = 0; rq < 4; ++rq)
#pragma unroll
            for (int j = 0; j < 4; ++j) {
                int cv = ch * 128 + cvb * 32 + rq * 8 + hi * 4 + j;
                accB[(size_t)cv * QB + qh * 32 + c] = acc[cvb][rq * 4 + j];
            }
    // l partials: hi halves hold complementary kv subsets -> distinct slots
    if (ch == 0) lP[(pb * 2 + hi) * QB + qh * 32 + c] = lacc;
}

// ---------------------------------------------------------------------------
// lred: lsum[b][n] = sum over (sp, hi) of lP
// ---------------------------------------------------------------------------
__global__ void lred(const float* __restrict__ lP, float* __restrict__ lsum,
                     int split) {
    int idx = blockIdx.x * 256 + threadIdx.x;
    if (idx >= NB * HWD) return;
    int b = idx / HWD, n = idx % HWD;
    int qblk = n >> 6, q = n & 63;
    size_t base = (size_t)(b * NQB + qblk) * split * 2 * QB + q;
    float s = 0.f;
    for (int i = 0; i < split * 2; ++i) s += lP[base + (size_t)i * QB];
    lsum[idx] = s;
}

// ---------------------------------------------------------------------------
// combine: sum fp32 split partials, divide, blend with last frame.
// ---------------------------------------------------------------------------
__global__ void combine(const float* __restrict__ accP, const float* __restrict__ lsum,
                        const float* __restrict__ mv, const float* __restrict__ up,
                        float* __restrict__ out, int split) {
    const int n = blockIdx.x * 256 + threadIdx.x;
    const int cv = blockIdx.y;
    const int b = blockIdx.z;
    const int qblk = n >> 6, q = n & 63;
    size_t base = ((size_t)(b * NQB + qblk) * split) * (CVD * QB) + (size_t)cv * QB + q;
    float a = 0.f;
    for (int sp = 0; sp < split; ++sp) a += accP[base + (size_t)sp * (CVD * QB)];
    float l = lsum[b * HWD + n];
    float p = up[b * HWD + n];
    float last = mv[((size_t)b * CVD + cv) * THWD + (TD - 1) * HWD + n];
    out[((size_t)b * CVD + cv) * HWD + n] = a / l * p + last * (1.f - p);
}

// ---------------------------------------------------------------------------
extern "C" void kernel_launch(void* const* d_in, const int* in_sizes, int n_in,
                              void* d_out, int out_size, void* d_ws,
                              size_t ws_size, hipStream_t stream) {
    const float* qk = (const float*)d_in[0];
    const float* qe = (const float*)d_in[1];
    const float* mk = (const float*)d_in[2];
    const float* ms = (const float*)d_in[3];
    const float* mv = (const float*)d_in[4];
    const float* up = (const float*)d_in[5];
    float* out = (float*)d_out;

    char* ws = (char*)d_ws;
    size_t off = 0;
    auto alloc = [&](size_t bytes) {
        size_t o = off;
        off += (bytes + 255) & ~(size_t)255;
        return o;
    };
    size_t kf_o = alloc((size_t)NB * THWD * 256);      // 9.4 MB
    size_t qf_o = alloc((size_t)NB * 72 * 8192);       // 1.2 MB
    size_t mvt_o = alloc((size_t)NB * 1152 * 8192);    // 18.9 MB
    size_t msf_o = alloc((size_t)NB * THWD * 4);
    size_t bsq_o = alloc((size_t)NB * HWD * 4);
    size_t ls_o = alloc((size_t)NB * HWD * 4);
    size_t fixed = off;

    // ws-adaptive split ladder: 16 -> 12 -> 8 (all divide 576 tiles evenly).
    // Bigger split = more blocks = more cross-block latency hiding.
    int split = 16;
    for (;;) {
        size_t need = fixed +
                      (((size_t)NB * NQB * split * 2 * QB * 4 + 255) & ~(size_t)255) +
                      (((size_t)NB * NQB * split * CVD * QB * 4 + 255) & ~(size_t)255);
        if (need <= ws_size || split == 8) break;
        split = (split == 16) ? 12 : 8;
    }
    int tiles = (THWD / split) / 32;   // split*tiles*32 == THWD exactly

    size_t lp_o = alloc((size_t)NB * NQB * split * 2 * QB * 4);
    size_t acc_o = alloc((size_t)NB * NQB * split * CVD * QB * 4);

    char* KFG = ws + kf_o;
    char* QFG = ws + qf_o;
    char* MVT = ws + mvt_o;
    float* msfp = (float*)(ws + msf_o);
    float* bsqp = (float*)(ws + bsq_o);
    float* lsump = (float*)(ws + ls_o);
    float* lPp = (float*)(ws + lp_o);
    float* accPp = (float*)(ws + acc_o);

    prep_kf<<<dim3(288, NB), 256, 0, stream>>>(mk, KFG);
    prep_qf<<<dim3(36, NB), 256, 0, stream>>>(qk, qe, QFG, bsqp);
    mv_t<<<dim3(288, 4, NB), 256, 0, stream>>>(mv, ms, MVT, msfp);

    fused<<<NB * NQB * split, 256, 0, stream>>>(KFG, QFG, MVT, msfp, bsqp, accPp,
                                                lPp, split, tiles);

    lred<<<(NB * HWD + 255) / 256, 256, 0, stream>>>(lPp, lsump, split);
    combine<<<dim3(HWD / 256, CVD, NB), 256, 0, stream>>>(accPp, lsump, mv, up, out,
                                                          split);
}

// Round 10
// 172.307 us; speedup vs baseline: 1.8666x; 1.8666x over previous
//
#include <hip/hip_runtime.h>
#include <math.h>

// (B, CK, CV, T, H, W) = (2, 64, 256, 8, 48, 48)
#define NB 2
#define CVD 256
#define TD 8
#define HWD 2304
#define THWD 18432
#define NQB 72            // q-blocks of 32
#define SPLIT 8
#define TILES 72          // (THWD/SPLIT)/32 kv-tiles of 32

typedef __bf16 bf16_t;
typedef __bf16 bf16x8 __attribute__((ext_vector_type(8)));
typedef float f32x4 __attribute__((ext_vector_type(4)));
typedef float f32x16 __attribute__((ext_vector_type(16)));
typedef unsigned u32;

__device__ __forceinline__ u32 cvtpk(float lo, float hi) {
    u32 r;
    asm("v_cvt_pk_bf16_f32 %0, %1, %2" : "=v"(r) : "v"(lo), "v"(hi));
    return r;
}
union U8 { u32 u[4]; bf16x8 v; };

// ---------------------------------------------------------------------------
// prep_kf: KFG[b][t32][ks 8][kv32 x hi 2]x16B  (1KB per (t32, ks), so the
// fused per-ks load is one fully-coalesced 1KB wave instruction).
// content ch = ks*16 + hi*8 + e: mk (ch<64) | mk^2 (ch>=64), bf16.
// ---------------------------------------------------------------------------
__global__ void prep_kf(const float* __restrict__ mk, char* __restrict__ KFG) {
    __shared__ float tile[64][65];
    const int b = blockIdx.y;
    const int kv0 = blockIdx.x * 64;
    const int tid = threadIdx.x;
    {
        const int ci = tid >> 2, seg = tid & 3;
        const float* src = mk + ((size_t)b * 64 + ci) * THWD + kv0;
#pragma unroll
        for (int j = 0; j < 4; ++j) {
            int chk = seg + j * 4;
            f32x4 v = *(const f32x4*)(src + chk * 4);
#pragma unroll
            for (int x = 0; x < 4; ++x) tile[ci][chk * 4 + x] = v[x];
        }
    }
    __syncthreads();
#pragma unroll
    for (int k = 0; k < 4; ++k) {
        int gid = k * 256 + tid;          // 1024 granules: 64 kv x 16 cg
        int kvl = gid >> 4, cg = gid & 15;
        bf16x8 o;
#pragma unroll
        for (int e = 0; e < 8; ++e) {
            int ch = cg * 8 + e;          // == ks*16 + hi*8 + e, cg = ks*2+hi
            float v;
            if (ch < 64) v = tile[ch][kvl];
            else { float m = tile[ch - 64][kvl]; v = m * m; }
            o[e] = (bf16_t)v;
        }
        int t = (kv0 + kvl) >> 5;         // global 32-kv tile index
        int ks = cg >> 1, h2 = cg & 1;
        size_t byte = ((size_t)b * 576 + t) * 8192 +
                      (size_t)((ks * 64 + (kvl & 31) * 2 + h2) << 4);
        *(bf16x8*)(KFG + byte) = o;
    }
}

// ---------------------------------------------------------------------------
// prep_qf: QFG[b][qb32][ks 8][q32][hi 2]x16B (direct 32x32x16 B-frag order),
// content ch = ks*16+hi*8+e: 2*qk*qe (ch<64) | -qe. bsq[b][q] fp32.
// ---------------------------------------------------------------------------
__global__ void prep_qf(const float* __restrict__ qk, const float* __restrict__ qe,
                        char* __restrict__ QFG, float* __restrict__ bsq) {
    __shared__ float tk[64][65];
    __shared__ float te[64][65];
    __shared__ float bs[4][64];
    const int b = blockIdx.y;
    const int q0 = blockIdx.x * 64;
    const int tid = threadIdx.x;
    {
        const int ci = tid >> 2, seg = tid & 3;
        const float* s1 = qk + ((size_t)b * 64 + ci) * HWD + q0;
        const float* s2 = qe + ((size_t)b * 64 + ci) * HWD + q0;
#pragma unroll
        for (int j = 0; j < 4; ++j) {
            int chk = seg + j * 4;
            f32x4 v1 = *(const f32x4*)(s1 + chk * 4);
            f32x4 v2 = *(const f32x4*)(s2 + chk * 4);
#pragma unroll
            for (int x = 0; x < 4; ++x) { tk[ci][chk * 4 + x] = v1[x]; te[ci][chk * 4 + x] = v2[x]; }
        }
    }
    __syncthreads();
    {
        int qls = tid & 63, cp = tid >> 6;
        float s = 0.f;
#pragma unroll
        for (int cc = 0; cc < 16; ++cc) {
            int ch = cp * 16 + cc;
            float kk = tk[ch][qls];
            s = fmaf(te[ch][qls] * kk, kk, s);
        }
        bs[cp][qls] = s;
    }
#pragma unroll
    for (int k = 0; k < 4; ++k) {
        int gid = k * 256 + tid;
        int qll = gid >> 4, G = gid & 15;
        int ks = G >> 1, h2 = G & 1;
        bf16x8 o;
#pragma unroll
        for (int e = 0; e < 8; ++e) {
            int ch = ks * 16 + h2 * 8 + e;
            float v;
            if (ch < 64) v = 2.f * tk[ch][qll] * te[ch][qll];
            else v = -te[ch - 64][qll];
            o[e] = (bf16_t)v;
        }
        size_t byte = ((size_t)b * NQB + (q0 >> 5) + (qll >> 5)) * 8192 +
                      (size_t)(((ks * 32 + (qll & 31)) * 2 + h2) * 16);
        *(bf16x8*)(QFG + byte) = o;
    }
    __syncthreads();
    if (tid < 64) bsq[b * HWD + q0 + tid] = bs[0][tid] + bs[1][tid] + bs[2][tid] + bs[3][tid];
}

// ---------------------------------------------------------------------------
// mv_t: MVT[b][t16][cv 256][hi 2]x16B (direct 32x32x16 A-frag order),
// content mv[cv][t16*16+hi*8+e] bf16.  Also msf = ms * 0.125 (fp32).
// ---------------------------------------------------------------------------
__global__ void mv_t(const float* __restrict__ mv, const float* __restrict__ ms,
                     char* __restrict__ MVT, float* __restrict__ msf) {
    __shared__ float tile[64][65];
    const int b = blockIdx.z;
    const int cv0 = blockIdx.y * 64;
    const int kv0 = blockIdx.x * 64;
    const int tid = threadIdx.x;
    {
        const int cvl = tid >> 2, seg = tid & 3;
        const float* src = mv + ((size_t)b * CVD + cv0 + cvl) * THWD + kv0;
#pragma unroll
        for (int j = 0; j < 4; ++j) {
            int chk = seg + j * 4;
            f32x4 v = *(const f32x4*)(src + chk * 4);
#pragma unroll
            for (int x = 0; x < 4; ++x) tile[cvl][chk * 4 + x] = v[x];
        }
    }
    if (blockIdx.y == 0 && tid < 64)
        msf[b * THWD + kv0 + tid] = ms[b * THWD + kv0 + tid] * 0.125f;
    __syncthreads();
#pragma unroll
    for (int k = 0; k < 2; ++k) {
        int gid = k * 256 + tid;          // 512 granules: 64 cv x 4 t16 x 2 hi
        int cvl = gid >> 3, gg = gid & 7;
        int t16l = gg >> 1, h2 = gg & 1;
        bf16x8 o;
#pragma unroll
        for (int e = 0; e < 8; ++e) o[e] = (bf16_t)tile[cvl][t16l * 16 + h2 * 8 + e];
        size_t byte = ((size_t)(b * 1152 + (kv0 >> 4) + t16l) * 256 + cv0 + cvl) * 32 +
                      (size_t)(h2 * 16);
        *(bf16x8*)(MVT + byte) = o;
    }
}

// ---------------------------------------------------------------------------
// fused: ONE WAVE per block, zero LDS, zero barriers. Wave = (b, sp, qb32, ch).
// Per 32-kv tile: kf + mv read straight from L2 (coalesced 1KB instructions),
// QK K=128 via dual MFMA chains, softmax in-register (exp -> cvt_pk ->
// permlane32_swap), PV K=32. Every wave is an independent stream; latency
// hiding comes from ~8 co-resident waves/CU, not intra-block pipelining.
// Scores <= 0 -> no max bookkeeping; split-T partials are plain sums.
// ---------------------------------------------------------------------------
__global__ __launch_bounds__(64, 2) void fused(
    const char* __restrict__ KFG, const char* __restrict__ QFG,
    const char* __restrict__ MVT, const float* __restrict__ msf,
    const float* __restrict__ bsq, float* __restrict__ accP,
    float* __restrict__ lP) {
    const int lane = threadIdx.x;
    const int c = lane & 31;
    const int hi = lane >> 5;

    // XCD swizzle: 288 consecutive ids per XCD = 2 (b,sp) groups (~3.5MB L2)
    const int bid = blockIdx.x;
    const int id = (bid & 7) * 288 + (bid >> 3);
    const int qch = id % 144;
    const int rest = id / 144;            // 0..15
    const int b = rest >> 3;
    const int sp = rest & 7;
    const int qb = qch >> 1;
    const int ch = qch & 1;
    const int t32base = sp * TILES;

    const char* KFb = KFG + (size_t)b * 576 * 8192;
    const char* qt = QFG + ((size_t)b * NQB + qb) * 8192;
    const char* MVb = MVT + (size_t)b * 1152 * 8192;
    const float* msfb = msf + (size_t)b * THWD;

    // all 8 q fragments resident (32 VGPR)
    bf16x8 qfr[8];
#pragma unroll
    for (int ks = 0; ks < 8; ++ks)
        qfr[ks] = *(const bf16x8*)(qt + ((ks * 32 + c) * 2 + hi) * 16);
    const float bsqr = bsq[b * HWD + qb * 32 + c];

    f32x16 acc[4];
#pragma unroll
    for (int i = 0; i < 4; ++i)
#pragma unroll
        for (int e = 0; e < 16; ++e) acc[i][e] = 0.f;
    float lacc = 0.f;

    for (int it = 0; it < TILES; ++it) {
        const int t0 = (t32base + it) * 32;
        const char* kt = KFb + (size_t)(t32base + it) * 8192;
        const char* mt = MVb + (size_t)(t0 >> 4) * 8192 + ((ch * 128 + c) * 2 + hi) * 16;

        // kf fragments: 8 coalesced 1KB loads (kv row = c, K-slice ks)
        bf16x8 kff[8];
#pragma unroll
        for (int ks = 0; ks < 8; ++ks)
            kff[ks] = *(const bf16x8*)(kt + ks * 1024 + (c * 2 + hi) * 16);
        // mv fragments: 8 coalesced 1KB loads (cv row = ch*128+cvb*32+c)
        bf16x8 mvf0[4], mvf1[4];
#pragma unroll
        for (int cvb = 0; cvb < 4; ++cvb) {
            mvf0[cvb] = *(const bf16x8*)(mt + cvb * 1024);
            mvf1[cvb] = *(const bf16x8*)(mt + 8192 + cvb * 1024);
        }

        // QK, dual independent accumulator chains
        f32x16 Sa, Sb;
#pragma unroll
        for (int e = 0; e < 16; ++e) { Sa[e] = 0.f; Sb[e] = 0.f; }
#pragma unroll
        for (int ks = 0; ks < 4; ++ks)
            Sa = __builtin_amdgcn_mfma_f32_32x32x16_bf16(kff[ks], qfr[ks], Sa, 0, 0, 0);
#pragma unroll
        for (int ks = 4; ks < 8; ++ks)
            Sb = __builtin_amdgcn_mfma_f32_32x32x16_bf16(kff[ks], qfr[ks], Sb, 0, 0, 0);

        // w = exp((S - bsq) * ms/8); scores <= 0 -> no max bookkeeping
        // S reg e -> kv = (e&3) + 8*(e>>2) + 4*hi, q col = c
        f32x16 S;
#pragma unroll
        for (int rq = 0; rq < 4; ++rq) {
            f32x4 m4 = *(const f32x4*)(msfb + t0 + rq * 8 + hi * 4);
#pragma unroll
            for (int j = 0; j < 4; ++j) {
                int e = rq * 4 + j;
                S[e] = __expf(((Sa[e] + Sb[e]) - bsqr) * m4[j]);
            }
        }
        if (ch == 0) {
#pragma unroll
            for (int e = 0; e < 16; ++e) lacc += S[e];
        }

        // pack to bf16 + permlane32_swap -> PV B-frags in-register
        u32 p[8];
#pragma unroll
        for (int j = 0; j < 8; ++j) p[j] = cvtpk(S[2 * j], S[2 * j + 1]);
        asm("v_permlane32_swap_b32 %0, %1" : "+v"(p[0]), "+v"(p[2]));
        asm("v_permlane32_swap_b32 %0, %1" : "+v"(p[1]), "+v"(p[3]));
        asm("v_permlane32_swap_b32 %0, %1" : "+v"(p[4]), "+v"(p[6]));
        asm("v_permlane32_swap_b32 %0, %1" : "+v"(p[5]), "+v"(p[7]));
        U8 wf0, wf1;
        wf0.u[0] = p[0]; wf0.u[1] = p[1]; wf0.u[2] = p[2]; wf0.u[3] = p[3];
        wf1.u[0] = p[4]; wf1.u[1] = p[5]; wf1.u[2] = p[6]; wf1.u[3] = p[7];

        // PV: acc[cv][q] += mv[cv][kv] * w[kv][q], K=32 as 2x K16
#pragma unroll
        for (int cvb = 0; cvb < 4; ++cvb)
            acc[cvb] = __builtin_amdgcn_mfma_f32_32x32x16_bf16(mvf0[cvb], wf0.v, acc[cvb], 0, 0, 0);
#pragma unroll
        for (int cvb = 0; cvb < 4; ++cvb)
            acc[cvb] = __builtin_amdgcn_mfma_f32_32x32x16_bf16(mvf1[cvb], wf1.v, acc[cvb], 0, 0, 0);
    }

    // epilogue: fp32 partial stores (each output element written once)
    const size_t pb = ((size_t)b * NQB + qb) * SPLIT + sp;
    float* accB = accP + pb * (CVD * 32);
#pragma unroll
    for (int cvb = 0; cvb < 4; ++cvb)
#pragma unroll
        for (int rq = 0; rq < 4; ++rq)
#pragma unroll
            for (int j = 0; j < 4; ++j) {
                int cv = ch * 128 + cvb * 32 + rq * 8 + hi * 4 + j;
                accB[(size_t)cv * 32 + c] = acc[cvb][rq * 4 + j];
            }
    // l partials: hi halves hold complementary kv subsets -> distinct slots
    if (ch == 0) lP[(pb * 2 + hi) * 32 + c] = lacc;
}

// ---------------------------------------------------------------------------
// lred: lsum[b][n] = sum over (sp, hi) of lP
// ---------------------------------------------------------------------------
__global__ void lred(const float* __restrict__ lP, float* __restrict__ lsum) {
    int idx = blockIdx.x * 256 + threadIdx.x;
    if (idx >= NB * HWD) return;
    int b = idx / HWD, n = idx % HWD;
    int qb = n >> 5, q = n & 31;
    size_t base = ((size_t)b * NQB + qb) * SPLIT * 64 + q;
    float s = 0.f;
#pragma unroll
    for (int i = 0; i < SPLIT * 2; ++i) s += lP[base + (size_t)i * 32];
    lsum[idx] = s;
}

// ---------------------------------------------------------------------------
// combine: sum fp32 split partials, divide, blend with last frame.
// ---------------------------------------------------------------------------
__global__ void combine(const float* __restrict__ accP, const float* __restrict__ lsum,
                        const float* __restrict__ mv, const float* __restrict__ up,
                        float* __restrict__ out) {
    const int n = blockIdx.x * 256 + threadIdx.x;
    const int cv = blockIdx.y;
    const int b = blockIdx.z;
    const int qb = n >> 5, nl = n & 31;
    size_t base = ((size_t)b * NQB + qb) * SPLIT * (CVD * 32) + (size_t)cv * 32 + nl;
    float a = 0.f;
#pragma unroll
    for (int sp = 0; sp < SPLIT; ++sp) a += accP[base + (size_t)sp * (CVD * 32)];
    float l = lsum[b * HWD + n];
    float p = up[b * HWD + n];
    float last = mv[((size_t)b * CVD + cv) * THWD + (TD - 1) * HWD + n];
    out[((size_t)b * CVD + cv) * HWD + n] = a / l * p + last * (1.f - p);
}

// ---------------------------------------------------------------------------
extern "C" void kernel_launch(void* const* d_in, const int* in_sizes, int n_in,
                              void* d_out, int out_size, void* d_ws,
                              size_t ws_size, hipStream_t stream) {
    const float* qk = (const float*)d_in[0];
    const float* qe = (const float*)d_in[1];
    const float* mk = (const float*)d_in[2];
    const float* ms = (const float*)d_in[3];
    const float* mv = (const float*)d_in[4];
    const float* up = (const float*)d_in[5];
    float* out = (float*)d_out;

    char* ws = (char*)d_ws;
    size_t off = 0;
    auto alloc = [&](size_t bytes) {
        size_t o = off;
        off += (bytes + 255) & ~(size_t)255;
        return o;
    };
    size_t kf_o = alloc((size_t)NB * 576 * 8192);      // 9.4 MB
    size_t qf_o = alloc((size_t)NB * NQB * 8192);      // 1.2 MB
    size_t mvt_o = alloc((size_t)NB * 1152 * 8192);    // 18.9 MB
    size_t msf_o = alloc((size_t)NB * THWD * 4);
    size_t bsq_o = alloc((size_t)NB * HWD * 4);
    size_t ls_o = alloc((size_t)NB * HWD * 4);
    size_t lp_o = alloc((size_t)NB * NQB * SPLIT * 64 * 4);
    size_t acc_o = alloc((size_t)NB * NQB * SPLIT * CVD * 32 * 4);  // 37.7 MB

    char* KFG = ws + kf_o;
    char* QFG = ws + qf_o;
    char* MVT = ws + mvt_o;
    float* msfp = (float*)(ws + msf_o);
    float* bsqp = (float*)(ws + bsq_o);
    float* lsump = (float*)(ws + ls_o);
    float* lPp = (float*)(ws + lp_o);
    float* accPp = (float*)(ws + acc_o);

    prep_kf<<<dim3(288, NB), 256, 0, stream>>>(mk, KFG);
    prep_qf<<<dim3(36, NB), 256, 0, stream>>>(qk, qe, QFG, bsqp);
    mv_t<<<dim3(288, 4, NB), 256, 0, stream>>>(mv, ms, MVT, msfp);

    // 2304 one-wave blocks: 2 b x 8 sp x 72 qb x 2 ch
    fused<<<NB * SPLIT * NQB * 2, 64, 0, stream>>>(KFG, QFG, MVT, msfp, bsqp,
                                                   accPp, lPp);

    lred<<<(NB * HWD + 255) / 256, 256, 0, stream>>>(lPp, lsump);
    combine<<<dim3(HWD / 256, CVD, NB), 256, 0, stream>>>(accPp, lsump, mv, up, out);
}